// Round 7
// baseline (641.137 us; speedup 1.0000x reference)
//
#include <hip/hip_runtime.h>

// GraphSAGE 3-layer: N=100000, E=3.2M, 128 -> 128 -> 128 -> 64.
// Round 7: fused bucket gather. fine_sort is folded into the gather:
// block = one 128-node coarse bucket (512 thr), loads packed edges to LDS,
// local 128-bin hist+scan+scatter, then segmented gather with LDS-resident
// indices (kills global index->feature dependent chain) and unroll x8
// (8 x 16B feature loads in flight/lane). sorted_src/row_ptr eliminated.
// Layer 3 transform-before-aggregate + merged weight prep kept from round 6.

#define NN 100000
#define CHUNK 8192
#define BCAP 6016  // bucket staging capacity (mean 4096, sigma~64; 30 sigma)

typedef _Float16 half_t;
typedef __attribute__((ext_vector_type(4))) _Float16 half4v;
typedef __attribute__((ext_vector_type(8))) _Float16 half8v;
typedef __attribute__((ext_vector_type(4))) float float4v;

// ---- Pass A: coarse histogram (LDS-privatized) ----
__global__ __launch_bounds__(256) void coarse_hist_kernel(const int* __restrict__ dst,
                                                          int* __restrict__ ghist, int E) {
    __shared__ int h[1024];
    int tid = threadIdx.x;
    for (int i = tid; i < 1024; i += 256) h[i] = 0;
    __syncthreads();
    int base = blockIdx.x * CHUNK;
    int nE = min(CHUNK, E - base);
    for (int i = tid; i < nE; i += 256) atomicAdd(&h[dst[base + i] >> 7], 1);
    __syncthreads();
    for (int i = tid; i < 1024; i += 256) {
        int v = h[i];
        if (v) atomicAdd(&ghist[i], v);
    }
}

// ---- Pass B: scan 1024 coarse bins -> cptr/cfill ----
__global__ __launch_bounds__(1024) void coarse_scan_kernel(const int* __restrict__ ghist,
                                                           int* __restrict__ cptr,
                                                           int* __restrict__ cfill, int E) {
    __shared__ int s[1024];
    int tid = threadIdx.x;
    s[tid] = ghist[tid];
    __syncthreads();
    for (int off = 1; off < 1024; off <<= 1) {
        int v = (tid >= off) ? s[tid - off] : 0;
        __syncthreads();
        s[tid] += v;
        __syncthreads();
    }
    int excl = (tid == 0) ? 0 : s[tid - 1];
    cptr[tid] = excl;
    cfill[tid] = excl;
    if (tid == 1023) cptr[1024] = s[1023];
}

// ---- Pass C: partition edges into coarse buckets (packed u32) ----
__global__ __launch_bounds__(256) void partition_kernel(const int* __restrict__ src,
                                                        const int* __restrict__ dst,
                                                        int* __restrict__ cfill,
                                                        unsigned int* __restrict__ coarse,
                                                        int E) {
    __shared__ int h[1024];
    __shared__ int off[1024];
    __shared__ int gbase[1024];
    __shared__ int ssum[256];
    __shared__ unsigned int stage[CHUNK];
    int tid = threadIdx.x;
    for (int i = tid; i < 1024; i += 256) h[i] = 0;
    __syncthreads();
    int base = blockIdx.x * CHUNK;
    int nE = min(CHUNK, E - base);
    for (int i = tid; i < nE; i += 256) atomicAdd(&h[dst[base + i] >> 7], 1);
    __syncthreads();
    int b0 = tid * 4;
    int sum = h[b0] + h[b0 + 1] + h[b0 + 2] + h[b0 + 3];
    ssum[tid] = sum;
    __syncthreads();
    for (int o = 1; o < 256; o <<= 1) {
        int v = (tid >= o) ? ssum[tid - o] : 0;
        __syncthreads();
        ssum[tid] += v;
        __syncthreads();
    }
    int run = (tid == 0) ? 0 : ssum[tid - 1];
#pragma unroll
    for (int j = 0; j < 4; j++) { off[b0 + j] = run; run += h[b0 + j]; }
    __syncthreads();
    for (int i = tid; i < nE; i += 256) {
        int d = dst[base + i];
        int s_ = src[base + i];
        int bin = d >> 7;
        int pos = atomicAdd(&off[bin], 1);
        stage[pos] = ((unsigned)(d & 127) << 17) | (unsigned)s_;
    }
    __syncthreads();
#pragma unroll
    for (int j = 0; j < 4; j++) {
        int b = b0 + j;
        if (h[b]) gbase[b] = atomicAdd(&cfill[b], h[b]);
    }
#pragma unroll
    for (int j = 0; j < 4; j++) {
        int b = b0 + j;
        int c = h[b];
        int lstart = off[b] - c;
        int gs = gbase[b];
        for (int k = 0; k < c; k++) coarse[gs + k] = stage[lstart + k];
    }
}

// ---- fused gather: block = one 128-node bucket; local fine sort in LDS,
//      then segmented mean-gather with LDS indices, unroll x8 ----
template <int C>  // feature width: 128 or 64
__global__ __launch_bounds__(512) void fused_gather(
    const half_t* __restrict__ h, const unsigned int* __restrict__ coarse,
    const int* __restrict__ cptr, half_t* __restrict__ mean, int n) {
    __shared__ unsigned int stage[BCAP];
    __shared__ int srcs[BCAP];
    __shared__ int fh[128];
    __shared__ int foff[128];
    int b = blockIdx.x;
    int beg = cptr[b], end = cptr[b + 1];
    int nb = min(end - beg, BCAP);
    int tid = threadIdx.x;
    for (int i = tid; i < nb; i += 512) stage[i] = coarse[beg + i];
    if (tid < 128) fh[tid] = 0;
    __syncthreads();
    for (int i = tid; i < nb; i += 512) atomicAdd(&fh[stage[i] >> 17], 1);
    __syncthreads();
    if (tid < 128) foff[tid] = fh[tid];
    __syncthreads();
    for (int o = 1; o < 128; o <<= 1) {
        int v = 0;
        if (tid < 128 && tid >= o) v = foff[tid - o];
        __syncthreads();
        if (tid < 128) foff[tid] += v;
        __syncthreads();
    }
    if (tid < 128) foff[tid] -= fh[tid];  // exclusive start -> fill counter
    __syncthreads();
    for (int i = tid; i < nb; i += 512) {
        unsigned int p = stage[i];
        int f = p >> 17;
        int pos = atomicAdd(&foff[f], 1);
        srcs[pos] = (int)(p & 0x1FFFF);
    }
    __syncthreads();
    // gather: 16 groups x 32 lanes; each group does 8 nodes sequentially
    constexpr int LPE = (C == 128) ? 16 : 8;  // lanes per edge (16B each)
    constexpr int NSUB = 32 / LPE;            // edge subgroups per group
    int g = tid >> 5;
    int lane = tid & 31;
    int sub = lane / LPE;
    int col = lane % LPE;
    const half_t* base = h + col * 8;
    for (int ni = 0; ni < 8; ni++) {
        int li = g * 8 + ni;
        int node = b * 128 + li;
        if (node >= n) break;
        int cntn = fh[li];
        int segEnd = foff[li];        // after scatter, foff = segment end
        int s0 = segEnd - cntn;
        float acc[8] = {0.f, 0.f, 0.f, 0.f, 0.f, 0.f, 0.f, 0.f};
        int j = s0 + sub;
        for (; j + NSUB * 7 < segEnd; j += NSUB * 8) {
            half8v v[8];
#pragma unroll
            for (int u = 0; u < 8; u++) {
                int s = srcs[j + NSUB * u];
                v[u] = *(const half8v*)(base + (size_t)s * C);
            }
#pragma unroll
            for (int u = 0; u < 8; u++)
#pragma unroll
                for (int e = 0; e < 8; e++) acc[e] += (float)v[u][e];
        }
        for (; j < segEnd; j += NSUB) {
            int s = srcs[j];
            half8v v0 = *(const half8v*)(base + (size_t)s * C);
#pragma unroll
            for (int e = 0; e < 8; e++) acc[e] += (float)v0[e];
        }
#pragma unroll
        for (int m = LPE; m < 32; m <<= 1)
#pragma unroll
            for (int e = 0; e < 8; e++) acc[e] += __shfl_xor(acc[e], m);
        if (sub == 0) {
            float inv = (cntn > 0) ? 1.0f / (float)cntn : 0.0f;
            half8v r = {(half_t)(acc[0] * inv), (half_t)(acc[1] * inv),
                        (half_t)(acc[2] * inv), (half_t)(acc[3] * inv),
                        (half_t)(acc[4] * inv), (half_t)(acc[5] * inv),
                        (half_t)(acc[6] * inv), (half_t)(acc[7] * inv)};
            *(half8v*)(mean + (size_t)node * C + col * 8) = r;
        }
    }
}

// ---- fp32 -> fp16 cast (row-major) ----
__global__ void cast_f2h(const float* __restrict__ in, half_t* __restrict__ out, int n4) {
    int t = blockIdx.x * blockDim.x + threadIdx.x;
    if (t < n4) {
        float4 v = *(const float4*)(in + (size_t)t * 4);
        half4v r = {(half_t)v.x, (half_t)v.y, (half_t)v.z, (half_t)v.w};
        *(half4v*)(out + (size_t)t * 4) = r;
    }
}

// ---- weight prep: fragment-contiguous fp16; all 6 weights in one launch ----
template <int C_IN, int C_OUT>
__device__ inline void prep_one(const float* __restrict__ W, half_t* __restrict__ B, int t) {
    constexpr int NCT = C_OUT / 16;
    if (t >= C_IN * C_OUT) return;
    int jj = t & 7;
    int kq = (t >> 3) & 3;
    int c = (t >> 5) & 15;
    int ct = (t >> 9) % NCT;
    int chunk = t / (512 * NCT);
    int k = chunk * 32 + kq * 8 + jj;
    int j = ct * 16 + c;
    B[t] = (half_t)W[(size_t)j * C_IN + k];
}

__global__ __launch_bounds__(256) void prep_all(
    const float* __restrict__ Wl1, const float* __restrict__ Wr1,
    const float* __restrict__ Wl2, const float* __restrict__ Wr2,
    const float* __restrict__ Wl3, const float* __restrict__ Wr3,
    half_t* Bl1, half_t* Br1, half_t* Bl2, half_t* Br2, half_t* Bl3, half_t* Br3) {
    int b = blockIdx.x;
    int tid = threadIdx.x;
    if (b < 256) {
        int sel = b >> 6;
        int t = (b & 63) * 256 + tid;
        const float* W = sel == 0 ? Wl1 : sel == 1 ? Wr1 : sel == 2 ? Wl2 : Wr2;
        half_t* B = sel == 0 ? Bl1 : sel == 1 ? Br1 : sel == 2 ? Bl2 : Br2;
        prep_one<128, 128>(W, B, t);
    } else {
        int idx = b - 256;
        int sel = idx >> 5;
        int t = (idx & 31) * 256 + tid;
        prep_one<128, 64>(sel == 0 ? Wl3 : Wr3, sel == 0 ? Bl3 : Br3, t);
    }
}

// ---- MFMA two-stage layer (layers 1,2) ----
template <int C_OUT>
__global__ __launch_bounds__(256) void mfma_layer(
    const half_t* __restrict__ rootA, const half_t* __restrict__ meanA,
    const half_t* __restrict__ Bl, const half_t* __restrict__ Br,
    const float* __restrict__ bias, half_t* __restrict__ out16, int n) {
    constexpr int NCT = C_OUT / 16;
    int tid = threadIdx.x;
    int w = tid >> 6;
    int l = tid & 63;
    int c = l & 15;
    int q = l >> 4;
    int row = blockIdx.x * 64 + w * 16 + c;
    int rowc = min(row, n - 1);

    float4v acc[NCT];
#pragma unroll
    for (int i = 0; i < NCT; i++) acc[i] = (float4v){0.f, 0.f, 0.f, 0.f};

#pragma unroll
    for (int s = 0; s < 2; s++) {
        const half_t* A = (s == 0 ? meanA : rootA) + (size_t)rowc * 128 + q * 8;
        const half_t* B = (s == 0 ? Bl : Br) + (size_t)(c * 4 + q) * 8;
#pragma unroll
        for (int ch = 0; ch < 4; ch++) {
            half8v a = *(const half8v*)(A + ch * 32);
            half8v b[NCT];
#pragma unroll
            for (int t2 = 0; t2 < NCT; t2++)
                b[t2] = *(const half8v*)(B + (size_t)ch * (NCT * 512) + t2 * 512);
#pragma unroll
            for (int t2 = 0; t2 < NCT; t2++)
                acc[t2] = __builtin_amdgcn_mfma_f32_16x16x32_f16(a, b[t2], acc[t2], 0, 0, 0);
        }
    }

    int orow0 = blockIdx.x * 64 + w * 16 + q * 4;
#pragma unroll
    for (int t2 = 0; t2 < NCT; t2++) {
        int col = t2 * 16 + c;
        float bv = bias[col];
#pragma unroll
        for (int r = 0; r < 4; r++) {
            int nrow = orow0 + r;
            if (nrow < n)
                out16[(size_t)nrow * C_OUT + col] = (half_t)fmaxf(acc[t2][r] + bv, 0.f);
        }
    }
}

// ---- MFMA single-stage (layer 3 pre/root) ----
template <int C_OUT, bool HAS_ADD, bool OUT32>
__global__ __launch_bounds__(256) void mfma_single(
    const half_t* __restrict__ A_, const half_t* __restrict__ Bp,
    const half_t* __restrict__ addv, const float* __restrict__ bias,
    float* __restrict__ out32, half_t* __restrict__ out16, int n) {
    constexpr int NCT = C_OUT / 16;
    int tid = threadIdx.x;
    int w = tid >> 6;
    int l = tid & 63;
    int c = l & 15;
    int q = l >> 4;
    int row = blockIdx.x * 64 + w * 16 + c;
    int rowc = min(row, n - 1);

    float4v acc[NCT];
#pragma unroll
    for (int i = 0; i < NCT; i++) acc[i] = (float4v){0.f, 0.f, 0.f, 0.f};

    const half_t* A = A_ + (size_t)rowc * 128 + q * 8;
    const half_t* B = Bp + (size_t)(c * 4 + q) * 8;
#pragma unroll
    for (int ch = 0; ch < 4; ch++) {
        half8v a = *(const half8v*)(A + ch * 32);
        half8v b[NCT];
#pragma unroll
        for (int t2 = 0; t2 < NCT; t2++)
            b[t2] = *(const half8v*)(B + (size_t)ch * (NCT * 512) + t2 * 512);
#pragma unroll
        for (int t2 = 0; t2 < NCT; t2++)
            acc[t2] = __builtin_amdgcn_mfma_f32_16x16x32_f16(a, b[t2], acc[t2], 0, 0, 0);
    }

    int orow0 = blockIdx.x * 64 + w * 16 + q * 4;
#pragma unroll
    for (int t2 = 0; t2 < NCT; t2++) {
        int col = t2 * 16 + c;
        float bv = bias ? bias[col] : 0.f;
#pragma unroll
        for (int r = 0; r < 4; r++) {
            int nrow = orow0 + r;
            if (nrow < n) {
                float v = acc[t2][r] + bv;
                if (HAS_ADD) v += (float)addv[(size_t)nrow * C_OUT + col];
                if (OUT32) out32[(size_t)nrow * C_OUT + col] = v;
                else       out16[(size_t)nrow * C_OUT + col] = (half_t)v;
            }
        }
    }
}

extern "C" void kernel_launch(void* const* d_in, const int* in_sizes, int n_in,
                              void* d_out, int out_size, void* d_ws, size_t ws_size,
                              hipStream_t stream) {
    const float* x   = (const float*)d_in[0];
    const int*   ei  = (const int*)d_in[1];
    const float* Wl1 = (const float*)d_in[2];
    const float* bl1 = (const float*)d_in[3];
    const float* Wr1 = (const float*)d_in[4];
    const float* Wl2 = (const float*)d_in[5];
    const float* bl2 = (const float*)d_in[6];
    const float* Wr2 = (const float*)d_in[7];
    const float* Wl3 = (const float*)d_in[8];
    const float* bl3 = (const float*)d_in[9];
    const float* Wr3 = (const float*)d_in[10];

    const int N = NN;
    const int E = in_sizes[1] / 2;
    const int* src = ei;
    const int* dst = ei + E;

    char* ws = (char*)d_ws;
    half_t* xh    = (half_t*)ws;                      // N*128
    half_t* hh    = xh + (size_t)N * 128;             // N*128
    half_t* meanh = hh + (size_t)N * 128;             // N*128 (z | meanz in layer 3)
    half_t* z     = meanh;                            // N*64
    half_t* meanz = meanh + (size_t)N * 64;           // N*64
    int* ghist    = (int*)(meanh + (size_t)N * 128);  // 1024
    int* cptr     = ghist + 1024;                     // 1025 (pad 1028)
    int* cfill    = cptr + 1028;                      // 1024
    unsigned int* coarse = (unsigned int*)(cfill + 1024);  // E
    half_t* Bl1 = (half_t*)(coarse + E);
    half_t* Br1 = Bl1 + 128 * 128;
    half_t* Bl2 = Br1 + 128 * 128;
    half_t* Br2 = Bl2 + 128 * 128;
    half_t* Bl3 = Br2 + 128 * 128;                    // 64*128
    half_t* Br3 = Bl3 + 64 * 128;

    // casts + weight prep
    cast_f2h<<<(N * 128 / 4 + 255) / 256, 256, 0, stream>>>(x, xh, N * 128 / 4);
    prep_all<<<320, 256, 0, stream>>>(Wl1, Wr1, Wl2, Wr2, Wl3, Wr3,
                                      Bl1, Br1, Bl2, Br2, Bl3, Br3);

    // CSR (bucket) build: hist -> scan -> partition. No fine sort (fused).
    const int sort_blocks = (E + CHUNK - 1) / CHUNK;
    hipMemsetAsync(ghist, 0, 1024 * 4, stream);
    coarse_hist_kernel<<<sort_blocks, 256, 0, stream>>>(dst, ghist, E);
    coarse_scan_kernel<<<1, 1024, 0, stream>>>(ghist, cptr, cfill, E);
    partition_kernel<<<sort_blocks, 256, 0, stream>>>(src, dst, cfill, coarse, E);

    const int nbuckets = (N + 127) / 128;  // 782
    const int gemm_blocks = (N + 63) / 64;

    // Layer 1: xh -> hh (relu)
    fused_gather<128><<<nbuckets, 512, 0, stream>>>(xh, coarse, cptr, meanh, N);
    mfma_layer<128><<<gemm_blocks, 256, 0, stream>>>(xh, meanh, Bl1, Br1, bl1, hh, N);

    // Layer 2: hh -> hh (relu)
    fused_gather<128><<<nbuckets, 512, 0, stream>>>(hh, coarse, cptr, meanh, N);
    mfma_layer<128><<<gemm_blocks, 256, 0, stream>>>(hh, meanh, Bl2, Br2, bl2, hh, N);

    // Layer 3: z = hh@Wl3^T ; meanz = gather-mean(z) ; out = meanz + bl3 + hh@Wr3^T
    mfma_single<64, false, false><<<gemm_blocks, 256, 0, stream>>>(
        hh, Bl3, nullptr, nullptr, nullptr, z, N);
    fused_gather<64><<<nbuckets, 512, 0, stream>>>(z, coarse, cptr, meanz, N);
    mfma_single<64, true, true><<<gemm_blocks, 256, 0, stream>>>(
        hh, Br3, meanz, bl3, (float*)d_out, nullptr, N);
}